// Round 13
// baseline (15840.231 us; speedup 1.0000x reference)
//
#include <hip/hip_runtime.h>
#include <hip/hip_bf16.h>

typedef unsigned short u16;
typedef unsigned int u32;
using short8 = __attribute__((ext_vector_type(8))) short;
using f32x4  = __attribute__((ext_vector_type(4))) float;

#define DEVINL static __device__ __forceinline__

DEVINL float bf2f(u16 u){
  union { unsigned int i; float f; } x; x.i = ((unsigned int)u) << 16; return x.f;
}
DEVINL u16 f2bf(float f){
  union { float f; unsigned int i; } x; x.f = f;
  unsigned int i = x.i;
  return (u16)((i + 0x7FFFu + ((i >> 16) & 1u)) >> 16);
}
DEVINL u16 f2bf1(float f){
  __hip_bfloat16 b = __float2bfloat16(f);
  u16 u; __builtin_memcpy(&u, &b, 2); return u;
}
DEVINL float fast_sigm(float x){
  float e = __builtin_amdgcn_exp2f(x * -1.442695041f);
  return __builtin_amdgcn_rcpf(1.f + e);
}
DEVINL float fast_tanh(float x){
  x = fminf(fmaxf(x, -10.f), 10.f);
  float e = __builtin_amdgcn_exp2f(x * -2.885390082f);
  return (1.f - e) * __builtin_amdgcn_rcpf(1.f + e);
}
DEVINL f32x4 zero4(){ f32x4 z = {0.f, 0.f, 0.f, 0.f}; return z; }

DEVINL f32x4 mfma16(short8 a, short8 b, f32x4 c){
  return __builtin_amdgcn_mfma_f32_16x16x32_bf16(a, b, c, 0, 0, 0);
}

// lane l: row = l&15, k0 = (l>>4)*8 ; 16B vector read. stride in u16 elements
DEVINL short8 frag_ld(const u16* base, int stride){
  int l = threadIdx.x & 63;
  return *(const short8*)(base + (l & 15) * stride + ((l >> 4) << 3));
}
DEVINL short8 gfrag(const u16* rowbase, int stride, int ks){
  int l = threadIdx.x & 63;
  return *(const short8*)(rowbase + (size_t)(l & 15) * stride + ks * 32 + ((l >> 4) << 3));
}

DEVINL void acc_store_lds(u16* dst, int stride, int col_base, f32x4 acc, float bias, bool relu){
  int l = threadIdx.x & 63;
  int col = col_base + (l & 15);
  int row0 = (l >> 4) * 4;
  #pragma unroll
  for (int r = 0; r < 4; r++){
    float v = acc[r] + bias;
    if (relu) v = fmaxf(v, 0.f);
    dst[(row0 + r) * stride + col] = f2bf(v);
  }
}

// workers: all blockDim threads participate
DEVINL void stage_weights(u16* dst, const float* src, int N, int K, int Kp){
  int stride = Kp + 8;
  if (Kp > K){
    int padw = Kp - K;
    for (int i = threadIdx.x; i < N * padw; i += blockDim.x){
      int n = i / padw, k = K + (i - (i / padw) * padw);
      dst[n * stride + k] = 0;
    }
  }
  for (int i = threadIdx.x * 4; i < N * K; i += blockDim.x * 4){
    float4 v = *(const float4*)(src + i);
    int n = i / K, k = i - n * K;
    u16* d = dst + n * stride + k;
    d[0] = f2bf(v.x); d[1] = f2bf(v.y); d[2] = f2bf(v.z); d[3] = f2bf(v.w);
  }
}

// gru: only threads 0..255 alive (K==Kp, no pad)
DEVINL void stage_weights256(u16* dst, const float* src, int N, int K){
  int stride = K + 8;
  for (int i = threadIdx.x * 4; i < N * K; i += 256 * 4){
    float4 v = *(const float4*)(src + i);
    int n = i / K, k = i - n * K;
    u16* d = dst + n * stride + k;
    d[0] = f2bf(v.x); d[1] = f2bf(v.y); d[2] = f2bf(v.z); d[3] = f2bf(v.w);
  }
}

__global__ __launch_bounds__(256) void k_inith(const float* __restrict__ h0, u16* __restrict__ hst){
  int i = blockIdx.x * 256 + threadIdx.x;
  if (i < 2 * 1024 * 128) hst[i] = f2bf(h0[i]);
}

// ================= role bodies (shared smem arena; idx = role-local block index) ==========

// ---- phi_u: 8 waves, 128 blocks ----
DEVINL void phiu_body(u16* smem, int idx, const float* u, const float* w0, const float* b0,
                      const float* w1, const float* b1, u16* phiW, int t0, int Tc){
  u16* w0s = smem;              // 5120
  u16* w1s = smem + 5120;       // 17408
  u16* buf = smem + 22528;      // 8 * 2176
  stage_weights(w0s, w0, 128, 16, 32);
  stage_weights(w1s, w1, 128, 128, 128);
  int wv = threadIdx.x >> 6, l = threadIdx.x & 63;
  u16* mybuf = buf + wv * 2176;
  float b0v[8], b1v[8];
  #pragma unroll
  for (int nt = 0; nt < 8; nt++){
    b0v[nt] = b0[nt * 16 + (l & 15)];
    b1v[nt] = b1[nt * 16 + (l & 15)];
  }
  __syncthreads();
  int tpb = Tc >> 4;
  int ntile = 1024 * tpb;
  for (int tile = idx * 8 + wv; tile < ntile; tile += 128 * 8){
    int b = tile / tpb;
    int tt = (tile - b * tpb) << 4;
    int t = l & 15, kb = l >> 4;
    #pragma unroll
    for (int j = 0; j < 4; j++){
      int k = kb + j * 4;
      mybuf[t * 136 + k] = f2bf(u[(size_t)(b * 16 + k) * 1024 + t0 + tt + t]);
      mybuf[t * 136 + 16 + k] = 0;
    }
    short8 a0 = frag_ld(mybuf, 136);
    f32x4 acc[8];
    #pragma unroll
    for (int nt = 0; nt < 8; nt++)
      acc[nt] = mfma16(a0, frag_ld(w0s + nt * 16 * 40, 40), zero4());
    #pragma unroll
    for (int nt = 0; nt < 8; nt++)
      acc_store_lds(mybuf, 136, nt * 16, acc[nt], b0v[nt], true);
    f32x4 a2[8];
    #pragma unroll
    for (int nt = 0; nt < 8; nt++) a2[nt] = zero4();
    #pragma unroll
    for (int ks = 0; ks < 4; ks++){
      short8 a = frag_ld(mybuf + ks * 32, 136);
      #pragma unroll
      for (int nt = 0; nt < 8; nt++)
        a2[nt] = mfma16(a, frag_ld(w1s + nt * 16 * 136 + ks * 32, 136), a2[nt]);
    }
    #pragma unroll
    for (int nt = 0; nt < 8; nt++)
      acc_store_lds(mybuf, 136, nt * 16, a2[nt], b1v[nt], false);
    u16* dst = phiW + (size_t)(b * Tc + tt) * 128;
    #pragma unroll
    for (int j = 0; j < 4; j++){
      int c = j * 64 + l;
      int row = c >> 4, k = (c & 15) * 8;
      *(short8*)(dst + row * 128 + k) = *(const short8*)(mybuf + row * 136 + k);
    }
  }
}

// ---- GRU: r11 internals, 64 blocks (threads 0..255 only) ----
DEVINL void gru_body(u16* smem, int idx, const u16* __restrict__ phi,
                     const float* gwih, const float* gwhh,
                     u16* hst, u16* Hs, int Tc){
  u16* wi0 = smem;                    // 384*136 = 52224
  u16* h0sA[2] = { smem + 52224, smem + 54400 };
  u16* h1sA[2] = { smem + 56576, smem + 58752 };
  u16* pbA[4]  = { smem + 60928, smem + 63104, smem + 65280, smem + 67456 };
  const int l = threadIdx.x & 63;
  const int wv = threadIdx.x >> 6;          // 0..3
  const int b0 = idx * 16;
  const int m0 = (l >> 4) * 4;
  const int cc = l & 15;
  const int nb = wv * 32;

  stage_weights256(wi0, gwih, 384, 128);    // layer0 W_ih in LDS

  const float* srcs[3] = { gwhh, gwih + 49152, gwhh + 49152 };
  short8 Wr[3][3][2][4];
  #pragma unroll
  for (int mm = 0; mm < 3; mm++){
    #pragma unroll
    for (int g = 0; g < 3; g++){
      #pragma unroll
      for (int nt = 0; nt < 2; nt++){
        int n = g * 128 + nb + nt * 16 + cc;
        #pragma unroll
        for (int ks = 0; ks < 4; ks++){
          const float* p = srcs[mm] + (size_t)n * 128 + ks * 32 + ((l >> 4) << 3);
          float4 va = *(const float4*)p;
          float4 vb = *(const float4*)(p + 4);
          short8 f;
          f[0] = (short)f2bf(va.x); f[1] = (short)f2bf(va.y);
          f[2] = (short)f2bf(va.z); f[3] = (short)f2bf(va.w);
          f[4] = (short)f2bf(vb.x); f[5] = (short)f2bf(vb.y);
          f[6] = (short)f2bf(vb.z); f[7] = (short)f2bf(vb.w);
          Wr[mm][g][nt][ks] = f;
        }
      }
    }
  }
  const int row = threadIdx.x >> 4, k0 = (threadIdx.x & 15) * 8;
  *(uint4*)(&h0sA[0][row * 136 + k0]) = *(const uint4*)(hst + (size_t)(b0 + row) * 128 + k0);
  *(uint4*)(&h1sA[0][row * 136 + k0]) = *(const uint4*)(hst + 131072 + (size_t)(b0 + row) * 128 + k0);
  float hp0[2][4], hp1[2][4];
  #pragma unroll
  for (int nt = 0; nt < 2; nt++)
    #pragma unroll
    for (int r = 0; r < 4; r++){
      hp0[nt][r] = bf2f(hst[(size_t)(b0 + m0 + r) * 128 + nb + nt * 16 + cc]);
      hp1[nt][r] = bf2f(hst[131072 + (size_t)(b0 + m0 + r) * 128 + nb + nt * 16 + cc]);
    }
  const u16* pL = phi + (size_t)(b0 + row) * Tc * 128 + k0;
  u16* Hp = Hs + (size_t)(b0 + row) * Tc * 128 + k0;
  *(uint4*)(&pbA[0][row * 136 + k0]) = *(const uint4*)(pL);
  *(uint4*)(&pbA[1][row * 136 + k0]) = *(const uint4*)(pL + 128);
  uint4 pfA = *(const uint4*)(pL + 2 * 128);
  uint4 pfB = *(const uint4*)(pL + 3 * 128);
  __syncthreads();

  auto ITER = [&](int i, int P, int q, uint4& pf){
    short8 a0[4];
    #pragma unroll
    for (int ks = 0; ks < 4; ks++) a0[ks] = frag_ld(h0sA[P] + ks * 32, 136);
    if (i > 0){
      short8 a1[4];
      #pragma unroll
      for (int ks = 0; ks < 4; ks++) a1[ks] = frag_ld(h1sA[P ^ 1] + ks * 32, 136);
      *(uint4*)(Hp + (size_t)(i - 1) * 128) = *(const uint4*)(&h1sA[P ^ 1][row * 136 + k0]);
      f32x4 cr[2], cz[2], cin[2], chn[2];
      #pragma unroll
      for (int nt = 0; nt < 2; nt++){ cr[nt]=zero4(); cz[nt]=zero4(); cin[nt]=zero4(); chn[nt]=zero4(); }
      #pragma unroll
      for (int ks = 0; ks < 4; ks++)
        #pragma unroll
        for (int nt = 0; nt < 2; nt++){
          cr[nt]  = mfma16(a0[ks], Wr[1][0][nt][ks], cr[nt]);
          cr[nt]  = mfma16(a1[ks], Wr[2][0][nt][ks], cr[nt]);
          cz[nt]  = mfma16(a0[ks], Wr[1][1][nt][ks], cz[nt]);
          cz[nt]  = mfma16(a1[ks], Wr[2][1][nt][ks], cz[nt]);
          cin[nt] = mfma16(a0[ks], Wr[1][2][nt][ks], cin[nt]);
          chn[nt] = mfma16(a1[ks], Wr[2][2][nt][ks], chn[nt]);
        }
      #pragma unroll
      for (int nt = 0; nt < 2; nt++)
        #pragma unroll
        for (int r = 0; r < 4; r++){
          float rg = fast_sigm(cr[nt][r]);
          float zg = fast_sigm(cz[nt][r]);
          float ng = fast_tanh(cin[nt][r] + rg * chn[nt][r]);
          float hv = zg * (hp1[nt][r] - ng) + ng;
          hp1[nt][r] = hv;
          h1sA[P][(m0 + r) * 136 + nb + nt * 16 + cc] = f2bf1(hv);
        }
    }
    if (i < Tc){
      short8 ap[4];
      #pragma unroll
      for (int ks = 0; ks < 4; ks++) ap[ks] = frag_ld(pbA[q] + ks * 32, 136);
      f32x4 cr[2], cz[2], cin[2], chn[2];
      #pragma unroll
      for (int nt = 0; nt < 2; nt++){ cr[nt]=zero4(); cz[nt]=zero4(); cin[nt]=zero4(); chn[nt]=zero4(); }
      #pragma unroll
      for (int ks = 0; ks < 4; ks++)
        #pragma unroll
        for (int nt = 0; nt < 2; nt++){
          cr[nt]  = mfma16(ap[ks], frag_ld(wi0 + (0 * 128 + nb + nt * 16) * 136 + ks * 32, 136), cr[nt]);
          cr[nt]  = mfma16(a0[ks], Wr[0][0][nt][ks], cr[nt]);
          cz[nt]  = mfma16(ap[ks], frag_ld(wi0 + (1 * 128 + nb + nt * 16) * 136 + ks * 32, 136), cz[nt]);
          cz[nt]  = mfma16(a0[ks], Wr[0][1][nt][ks], cz[nt]);
          cin[nt] = mfma16(ap[ks], frag_ld(wi0 + (2 * 128 + nb + nt * 16) * 136 + ks * 32, 136), cin[nt]);
          chn[nt] = mfma16(a0[ks], Wr[0][2][nt][ks], chn[nt]);
        }
      if (i + 2 < Tc) *(uint4*)(&pbA[(q + 2) & 3][row * 136 + k0]) = pf;
      if (i + 4 < Tc) pf = *(const uint4*)(pL + (size_t)(i + 4) * 128);
      #pragma unroll
      for (int nt = 0; nt < 2; nt++)
        #pragma unroll
        for (int r = 0; r < 4; r++){
          float rg = fast_sigm(cr[nt][r]);
          float zg = fast_sigm(cz[nt][r]);
          float ng = fast_tanh(cin[nt][r] + rg * chn[nt][r]);
          float hv = zg * (hp0[nt][r] - ng) + ng;
          hp0[nt][r] = hv;
          h0sA[P ^ 1][(m0 + r) * 136 + nb + nt * 16 + cc] = f2bf1(hv);
        }
    }
    __builtin_amdgcn_sched_barrier(0);
    asm volatile("s_waitcnt lgkmcnt(0)");
    __builtin_amdgcn_s_barrier();
    __builtin_amdgcn_sched_barrier(0);
  };

  for (int i = 0; i < Tc; i += 4){
    ITER(i + 0, 0, 0, pfA);
    ITER(i + 1, 1, 1, pfB);
    ITER(i + 2, 0, 2, pfA);
    ITER(i + 3, 1, 3, pfB);
  }
  ITER(Tc, 0, 0, pfA);
  *(uint4*)(hst + (size_t)(b0 + row) * 128 + k0) = *(const uint4*)(&h0sA[0][row * 136 + k0]);
  *(uint4*)(hst + 131072 + (size_t)(b0 + row) * 128 + k0) = *(const uint4*)(&h1sA[0][row * 136 + k0]);
}

// ---- c1: 8 waves, 128 blocks ----
DEVINL void c1_body(u16* smem, int idx, const u16* phiC, const u16* HsC,
    const float* dw0, const float* db0, const float* dw1, const float* db1,
    const float* xmw, const float* xmb, const float* xlw, const float* xlb,
    u16* xmlv, int Tc){
  u16* w0s = smem;             // 33792
  u16* w1s = smem + 33792;     // 17408
  u16* xws = smem + 51200;     // 4352
  u16* buf = smem + 55552;     // 8*2176
  stage_weights(w0s, dw0, 128, 256, 256);
  stage_weights(w1s, dw1, 128, 128, 128);
  stage_weights(xws, xmw, 16, 128, 128);
  stage_weights(xws + 16 * 136, xlw, 16, 128, 128);
  int wv = threadIdx.x >> 6, l = threadIdx.x & 63;
  u16* mybuf = buf + wv * 2176;
  float b0v[8], b1v[8];
  #pragma unroll
  for (int nt = 0; nt < 8; nt++){
    b0v[nt] = db0[nt * 16 + (l & 15)];
    b1v[nt] = db1[nt * 16 + (l & 15)];
  }
  float bxm = xmb[l & 15], bxl = xlb[l & 15];
  __syncthreads();
  int tpb = Tc >> 4;
  int ntile = 1024 * tpb;
  for (int tile = idx * 8 + wv; tile < ntile; tile += 128 * 8){
    int b = tile / tpb;
    int tt = (tile - b * tpb) << 4;
    size_t rbase = (size_t)(b * Tc + tt);
    const u16* ap = phiC + rbase * 128;
    const u16* hp = HsC + rbase * 128;
    f32x4 acc[8];
    #pragma unroll
    for (int nt = 0; nt < 8; nt++) acc[nt] = zero4();
    #pragma unroll
    for (int ks = 0; ks < 8; ks++){
      short8 a = (ks < 4) ? gfrag(ap, 128, ks) : gfrag(hp, 128, ks - 4);
      #pragma unroll
      for (int nt = 0; nt < 8; nt++)
        acc[nt] = mfma16(a, frag_ld(w0s + nt * 16 * 264 + ks * 32, 264), acc[nt]);
    }
    #pragma unroll
    for (int nt = 0; nt < 8; nt++)
      acc_store_lds(mybuf, 136, nt * 16, acc[nt], b0v[nt], true);
    f32x4 a2[8];
    #pragma unroll
    for (int nt = 0; nt < 8; nt++) a2[nt] = zero4();
    #pragma unroll
    for (int ks = 0; ks < 4; ks++){
      short8 a = frag_ld(mybuf + ks * 32, 136);
      #pragma unroll
      for (int nt = 0; nt < 8; nt++)
        a2[nt] = mfma16(a, frag_ld(w1s + nt * 16 * 136 + ks * 32, 136), a2[nt]);
    }
    #pragma unroll
    for (int nt = 0; nt < 8; nt++)
      acc_store_lds(mybuf, 136, nt * 16, a2[nt], b1v[nt], false);
    f32x4 am = zero4(), al = zero4();
    #pragma unroll
    for (int ks = 0; ks < 4; ks++){
      short8 a = frag_ld(mybuf + ks * 32, 136);
      am = mfma16(a, frag_ld(xws + ks * 32, 136), am);
      al = mfma16(a, frag_ld(xws + 16 * 136 + ks * 32, 136), al);
    }
    acc_store_lds(mybuf, 136, 0, am, bxm, false);
    acc_store_lds(mybuf, 136, 16, al, bxl, false);
    u16* dst = xmlv + rbase * 32;
    int c = l;
    int row = c >> 2, k = (c & 3) * 8;
    *(short8*)(dst + row * 32 + k) = *(const short8*)(mybuf + row * 136 + k);
  }
}

// ---- c2: 8 waves, 128 blocks ----
DEVINL void c2_body(u16* smem, int idx, const u16* xmlv, const float* y,
    const float* pw0, const float* pb0, const float* pw1, const float* pb1,
    const float* mw0, const float* mb0, const float* mw1, const float* mb1,
    const float* Cw, float* out, int t0, int Tc){
  u16* pw0s = smem;            // 5120
  u16* pw1s = smem + 5120;     // 17408
  u16* mw0s = smem + 22528;    // 17408
  u16* mw1s = smem + 39936;    // 2176
  u16* Cs   = smem + 42112;    // 640
  u16* buf  = smem + 42752;    // 8*2176
  stage_weights(pw0s, pw0, 128, 32, 32);
  stage_weights(pw1s, pw1, 128, 128, 128);
  stage_weights(mw0s, mw0, 128, 128, 128);
  stage_weights(mw1s, mw1, 16, 128, 128);
  stage_weights(Cs, Cw, 16, 16, 32);
  int wv = threadIdx.x >> 6, l = threadIdx.x & 63;
  u16* mybuf = buf + wv * 2176;
  float bp0v[8], bp1v[8], bm0v[8];
  #pragma unroll
  for (int nt = 0; nt < 8; nt++){
    bp0v[nt] = pb0[nt * 16 + (l & 15)];
    bp1v[nt] = pb1[nt * 16 + (l & 15)];
    bm0v[nt] = mb0[nt * 16 + (l & 15)];
  }
  float bm1 = mb1[l & 15];
  __syncthreads();
  float lacc = 0.f;
  int tpb = Tc >> 4;
  int ntile = 1024 * tpb;
  for (int tile = idx * 8 + wv; tile < ntile; tile += 128 * 8){
    int b = tile / tpb;
    int tt = (tile - b * tpb) << 4;
    size_t rbase = (size_t)(b * Tc + tt);
    const u16* xp = xmlv + rbase * 32;
    short8 a0 = gfrag(xp, 32, 0);
    f32x4 acc[8];
    #pragma unroll
    for (int nt = 0; nt < 8; nt++)
      acc[nt] = mfma16(a0, frag_ld(pw0s + nt * 16 * 40, 40), zero4());
    #pragma unroll
    for (int nt = 0; nt < 8; nt++)
      acc_store_lds(mybuf, 136, nt * 16, acc[nt], bp0v[nt], true);
    f32x4 a2[8];
    #pragma unroll
    for (int nt = 0; nt < 8; nt++) a2[nt] = zero4();
    #pragma unroll
    for (int ks = 0; ks < 4; ks++){
      short8 a = frag_ld(mybuf + ks * 32, 136);
      #pragma unroll
      for (int nt = 0; nt < 8; nt++)
        a2[nt] = mfma16(a, frag_ld(pw1s + nt * 16 * 136 + ks * 32, 136), a2[nt]);
    }
    #pragma unroll
    for (int nt = 0; nt < 8; nt++)
      acc_store_lds(mybuf, 136, nt * 16, a2[nt], bp1v[nt], false);
    f32x4 a3[8];
    #pragma unroll
    for (int nt = 0; nt < 8; nt++) a3[nt] = zero4();
    #pragma unroll
    for (int ks = 0; ks < 4; ks++){
      short8 a = frag_ld(mybuf + ks * 32, 136);
      #pragma unroll
      for (int nt = 0; nt < 8; nt++)
        a3[nt] = mfma16(a, frag_ld(mw0s + nt * 16 * 136 + ks * 32, 136), a3[nt]);
    }
    #pragma unroll
    for (int nt = 0; nt < 8; nt++)
      acc_store_lds(mybuf, 136, nt * 16, a3[nt], bm0v[nt], true);
    f32x4 ay = zero4();
    #pragma unroll
    for (int ks = 0; ks < 4; ks++){
      short8 a = frag_ld(mybuf + ks * 32, 136);
      ay = mfma16(a, frag_ld(mw1s + ks * 32, 136), ay);
    }
    f32x4 ac = mfma16(a0, frag_ld(Cs, 40), zero4());
    #pragma unroll
    for (int r = 0; r < 4; r++){
      float yh = ay[r] + bm1 + ac[r];
      int m = (l >> 4) * 4 + r, j = l & 15;
      float d = yh - y[(size_t)(b * 16 + j) * 1024 + t0 + tt + m];
      lacc += d * d;
    }
  }
  #pragma unroll
  for (int off = 32; off > 0; off >>= 1)
    lacc += __shfl_down(lacc, off);
  if (l == 0) atomicAdd(out, lacc);
}

// ================= fused pipeline kernel =================
// launch j: phiu(j) | gru(j-1) | c1(j-2) | c2(j-3).
// XCD partition: gru at blockIdx%8 in {0,1} (XCD 0-1 exclusive); workers on XCD 2-7.
__global__ __launch_bounds__(512, 1) void k_fused(
    const float* __restrict__ u, const float* __restrict__ y,
    const float* puw0, const float* pub0, const float* puw1, const float* pub1,
    const float* dw0, const float* db0, const float* dw1, const float* db1,
    const float* xmw, const float* xmb, const float* xlw, const float* xlb,
    const float* pxw0, const float* pxb0, const float* pxw1, const float* pxb1,
    const float* mw0, const float* mb0, const float* mw1, const float* mb1,
    const float* Cw, const float* gwih, const float* gwhh,
    u16* phiW, const u16* phiG, const u16* phiC,
    u16* hst, u16* HsW, const u16* HsC,
    u16* xmW, const u16* xmC,
    float* out, int t0phiu, int t0c2, int Tc, int flags){
  __shared__ __align__(16) u16 smem[72960];   // 145920 B arena
  int bi = blockIdx.x;
  if (bi < 256 && (bi & 7) < 2){
    if (!(flags & 2)) return;
    if (threadIdx.x >= 256) return;
    int idx = ((bi >> 3) << 1) | (bi & 1);
    gru_body(smem, idx, phiG, gwih, gwhh, hst, HsW, Tc);
  } else {
    int w = (bi < 256) ? ((bi >> 3) * 6 + (bi & 7) - 2) : (192 + bi - 256);
    int role = w >> 7, idx = w & 127;
    if (role == 0){
      if (flags & 1) phiu_body(smem, idx, u, puw0, pub0, puw1, pub1, phiW, t0phiu, Tc);
    } else if (role == 1){
      if (flags & 4) c1_body(smem, idx, phiC, HsC, dw0, db0, dw1, db1, xmw, xmb, xlw, xlb, xmW, Tc);
    } else {
      if (flags & 8) c2_body(smem, idx, xmC, y, pxw0, pxb0, pxw1, pxb1, mw0, mb0, mw1, mb1, Cw, out, t0c2, Tc);
    }
  }
}

extern "C" void kernel_launch(void* const* d_in, const int* in_sizes, int n_in,
                              void* d_out, int out_size, void* d_ws, size_t ws_size,
                              hipStream_t stream){
  const float* u    = (const float*)d_in[0];
  const float* y    = (const float*)d_in[1];
  const float* h0   = (const float*)d_in[2];
  const float* puw0 = (const float*)d_in[3];
  const float* pub0 = (const float*)d_in[4];
  const float* puw1 = (const float*)d_in[5];
  const float* pub1 = (const float*)d_in[6];
  const float* dw0  = (const float*)d_in[7];
  const float* db0  = (const float*)d_in[8];
  const float* dw1  = (const float*)d_in[9];
  const float* db1  = (const float*)d_in[10];
  const float* xmw  = (const float*)d_in[11];
  const float* xmb  = (const float*)d_in[12];
  const float* xlw  = (const float*)d_in[13];
  const float* xlb  = (const float*)d_in[14];
  const float* pxw0 = (const float*)d_in[15];
  const float* pxb0 = (const float*)d_in[16];
  const float* pxw1 = (const float*)d_in[17];
  const float* pxb1 = (const float*)d_in[18];
  const float* mw0  = (const float*)d_in[19];
  const float* mb0  = (const float*)d_in[20];
  const float* mw1  = (const float*)d_in[21];
  const float* mb1  = (const float*)d_in[22];
  const float* gwih = (const float*)d_in[23];
  const float* gwhh = (const float*)d_in[24];
  const float* Cw   = (const float*)d_in[25];

  const size_t hstE = (size_t)2 * 1024 * 128;
  int Tc = 128;
  while (Tc > 16){
    size_t needB = (hstE + (size_t)1024 * Tc * (3 * 128 + 2 * 128 + 2 * 32)) * 2 + 4096;
    if (needB <= ws_size) break;
    Tc >>= 1;
  }
  int NC = 1024 / Tc;
  size_t phiSz = (size_t)1024 * Tc * 128;   // elems; Hs slot same size
  size_t xmSz  = (size_t)1024 * Tc * 32;

  u16* hst  = (u16*)d_ws;
  u16* phiB = hst + hstE;
  u16* HsB  = phiB + 3 * phiSz;
  u16* xmB  = HsB + 2 * phiSz;

  hipMemsetAsync(d_out, 0, sizeof(float), stream);
  k_inith<<<1024, 256, 0, stream>>>(h0, hst);

  for (int j = 0; j <= NC + 2; j++){
    int flags = 0;
    if (j < NC) flags |= 1;                    // phiu(j)
    if (j >= 1 && j <= NC) flags |= 2;         // gru(j-1)
    if (j >= 2 && j <= NC + 1) flags |= 4;     // c1(j-2)
    if (j >= 3) flags |= 8;                    // c2(j-3)
    int s0 = j % 3, s1 = (j + 2) % 3, s2 = (j + 1) % 3;
    int hw = (j + 1) & 1, hc = j & 1;
    int xw = j & 1, xc = (j + 1) & 1;
    k_fused<<<448, 512, 0, stream>>>(
        u, y,
        puw0, pub0, puw1, pub1,
        dw0, db0, dw1, db1, xmw, xmb, xlw, xlb,
        pxw0, pxb0, pxw1, pxb1, mw0, mb0, mw1, mb1,
        Cw, gwih, gwhh,
        phiB + (size_t)s0 * phiSz, phiB + (size_t)s1 * phiSz, phiB + (size_t)s2 * phiSz,
        hst, HsB + (size_t)hw * phiSz, HsB + (size_t)hc * phiSz,
        xmB + (size_t)xw * xmSz, xmB + (size_t)xc * xmSz,
        (float*)d_out, j * Tc, (j - 3) * Tc, Tc, flags);
  }
}

// Round 14
// 3358.244 us; speedup vs baseline: 4.7168x; 4.7168x over previous
//
#include <hip/hip_runtime.h>
#include <hip/hip_bf16.h>

typedef unsigned short u16;
typedef unsigned int u32;
using short8 = __attribute__((ext_vector_type(8))) short;
using f32x4  = __attribute__((ext_vector_type(4))) float;

#define DEVINL static __device__ __forceinline__

DEVINL float bf2f(u16 u){
  union { unsigned int i; float f; } x; x.i = ((unsigned int)u) << 16; return x.f;
}
DEVINL u16 f2bf(float f){
  union { float f; unsigned int i; } x; x.f = f;
  unsigned int i = x.i;
  return (u16)((i + 0x7FFFu + ((i >> 16) & 1u)) >> 16);
}
DEVINL u16 f2bf1(float f){
  __hip_bfloat16 b = __float2bfloat16(f);
  u16 u; __builtin_memcpy(&u, &b, 2); return u;
}
DEVINL float fast_sigm(float x){
  float e = __builtin_amdgcn_exp2f(x * -1.442695041f);
  return __builtin_amdgcn_rcpf(1.f + e);
}
DEVINL float fast_tanh(float x){
  x = fminf(fmaxf(x, -10.f), 10.f);
  float e = __builtin_amdgcn_exp2f(x * -2.885390082f);
  return (1.f - e) * __builtin_amdgcn_rcpf(1.f + e);
}
DEVINL f32x4 zero4(){ f32x4 z = {0.f, 0.f, 0.f, 0.f}; return z; }

DEVINL f32x4 mfma16(short8 a, short8 b, f32x4 c){
  return __builtin_amdgcn_mfma_f32_16x16x32_bf16(a, b, c, 0, 0, 0);
}

// lane l: row = l&15, k0 = (l>>4)*8 ; 16B vector read. stride in u16 elements
DEVINL short8 frag_ld(const u16* base, int stride){
  int l = threadIdx.x & 63;
  return *(const short8*)(base + (l & 15) * stride + ((l >> 4) << 3));
}
DEVINL short8 gfrag(const u16* rowbase, int stride, int ks){
  int l = threadIdx.x & 63;
  return *(const short8*)(rowbase + (size_t)(l & 15) * stride + ks * 32 + ((l >> 4) << 3));
}

DEVINL void acc_store_lds(u16* dst, int stride, int col_base, f32x4 acc, float bias, bool relu){
  int l = threadIdx.x & 63;
  int col = col_base + (l & 15);
  int row0 = (l >> 4) * 4;
  #pragma unroll
  for (int r = 0; r < 4; r++){
    float v = acc[r] + bias;
    if (relu) v = fmaxf(v, 0.f);
    dst[(row0 + r) * stride + col] = f2bf(v);
  }
}

DEVINL void stage_weights(u16* dst, const float* src, int N, int K, int Kp){
  int stride = Kp + 8;
  if (Kp > K){
    int padw = Kp - K;
    for (int i = threadIdx.x; i < N * padw; i += blockDim.x){
      int n = i / padw, k = K + (i - (i / padw) * padw);
      dst[n * stride + k] = 0;
    }
  }
  for (int i = threadIdx.x * 4; i < N * K; i += blockDim.x * 4){
    float4 v = *(const float4*)(src + i);
    int n = i / K, k = i - n * K;
    u16* d = dst + n * stride + k;
    d[0] = f2bf(v.x); d[1] = f2bf(v.y); d[2] = f2bf(v.z); d[3] = f2bf(v.w);
  }
}

__global__ __launch_bounds__(256) void k_inith(const float* __restrict__ h0, u16* __restrict__ hst){
  int i = blockIdx.x * 256 + threadIdx.x;
  if (i < 2 * 1024 * 128) hst[i] = f2bf(h0[i]);
}

// ================= role bodies (shared smem arena; idx = role-local block index) ==========

// ---- phi_u: 4 waves, 112 blocks ----
DEVINL void phiu_body(u16* smem, int idx, const float* u, const float* w0, const float* b0,
                      const float* w1, const float* b1, u16* phiW, int t0, int Tc){
  u16* w0s = smem;              // 5120
  u16* w1s = smem + 5120;       // 17408
  u16* buf = smem + 22528;      // 4 * 2176
  stage_weights(w0s, w0, 128, 16, 32);
  stage_weights(w1s, w1, 128, 128, 128);
  int wv = threadIdx.x >> 6, l = threadIdx.x & 63;
  u16* mybuf = buf + wv * 2176;
  float b0v[8], b1v[8];
  #pragma unroll
  for (int nt = 0; nt < 8; nt++){
    b0v[nt] = b0[nt * 16 + (l & 15)];
    b1v[nt] = b1[nt * 16 + (l & 15)];
  }
  __syncthreads();
  int tpb = Tc >> 4;
  int ntile = 1024 * tpb;
  for (int tile = idx * 4 + wv; tile < ntile; tile += 112 * 4){
    int b = tile / tpb;
    int tt = (tile - b * tpb) << 4;
    int t = l & 15, kb = l >> 4;
    #pragma unroll
    for (int j = 0; j < 4; j++){
      int k = kb + j * 4;
      mybuf[t * 136 + k] = f2bf(u[(size_t)(b * 16 + k) * 1024 + t0 + tt + t]);
      mybuf[t * 136 + 16 + k] = 0;
    }
    short8 a0 = frag_ld(mybuf, 136);
    f32x4 acc[8];
    #pragma unroll
    for (int nt = 0; nt < 8; nt++)
      acc[nt] = mfma16(a0, frag_ld(w0s + nt * 16 * 40, 40), zero4());
    #pragma unroll
    for (int nt = 0; nt < 8; nt++)
      acc_store_lds(mybuf, 136, nt * 16, acc[nt], b0v[nt], true);
    f32x4 a2[8];
    #pragma unroll
    for (int nt = 0; nt < 8; nt++) a2[nt] = zero4();
    #pragma unroll
    for (int ks = 0; ks < 4; ks++){
      short8 a = frag_ld(mybuf + ks * 32, 136);
      #pragma unroll
      for (int nt = 0; nt < 8; nt++)
        a2[nt] = mfma16(a, frag_ld(w1s + nt * 16 * 136 + ks * 32, 136), a2[nt]);
    }
    #pragma unroll
    for (int nt = 0; nt < 8; nt++)
      acc_store_lds(mybuf, 136, nt * 16, a2[nt], b1v[nt], false);
    u16* dst = phiW + (size_t)(b * Tc + tt) * 128;
    #pragma unroll
    for (int j = 0; j < 4; j++){
      int c = j * 64 + l;
      int row = c >> 4, k = (c & 15) * 8;
      *(short8*)(dst + row * 128 + k) = *(const short8*)(mybuf + row * 136 + k);
    }
  }
}

// ---- GRU: r11 internals verbatim, 64 blocks ----
DEVINL void gru_body(u16* smem, int idx, const u16* __restrict__ phi,
                     const float* gwih, const float* gwhh,
                     u16* hst, u16* Hs, int Tc){
  u16* wi0 = smem;                    // 384*136 = 52224
  u16* h0sA[2] = { smem + 52224, smem + 54400 };
  u16* h1sA[2] = { smem + 56576, smem + 58752 };
  u16* pbA[4]  = { smem + 60928, smem + 63104, smem + 65280, smem + 67456 };
  const int l = threadIdx.x & 63;
  const int wv = threadIdx.x >> 6;          // 0..3
  const int b0 = idx * 16;
  const int m0 = (l >> 4) * 4;
  const int cc = l & 15;
  const int nb = wv * 32;

  stage_weights(wi0, gwih, 384, 128, 128);  // layer0 W_ih in LDS

  const float* srcs[3] = { gwhh, gwih + 49152, gwhh + 49152 };
  short8 Wr[3][3][2][4];
  #pragma unroll
  for (int mm = 0; mm < 3; mm++){
    #pragma unroll
    for (int g = 0; g < 3; g++){
      #pragma unroll
      for (int nt = 0; nt < 2; nt++){
        int n = g * 128 + nb + nt * 16 + cc;
        #pragma unroll
        for (int ks = 0; ks < 4; ks++){
          const float* p = srcs[mm] + (size_t)n * 128 + ks * 32 + ((l >> 4) << 3);
          float4 va = *(const float4*)p;
          float4 vb = *(const float4*)(p + 4);
          short8 f;
          f[0] = (short)f2bf(va.x); f[1] = (short)f2bf(va.y);
          f[2] = (short)f2bf(va.z); f[3] = (short)f2bf(va.w);
          f[4] = (short)f2bf(vb.x); f[5] = (short)f2bf(vb.y);
          f[6] = (short)f2bf(vb.z); f[7] = (short)f2bf(vb.w);
          Wr[mm][g][nt][ks] = f;
        }
      }
    }
  }
  const int row = threadIdx.x >> 4, k0 = (threadIdx.x & 15) * 8;
  *(uint4*)(&h0sA[0][row * 136 + k0]) = *(const uint4*)(hst + (size_t)(b0 + row) * 128 + k0);
  *(uint4*)(&h1sA[0][row * 136 + k0]) = *(const uint4*)(hst + 131072 + (size_t)(b0 + row) * 128 + k0);
  float hp0[2][4], hp1[2][4];
  #pragma unroll
  for (int nt = 0; nt < 2; nt++)
    #pragma unroll
    for (int r = 0; r < 4; r++){
      hp0[nt][r] = bf2f(hst[(size_t)(b0 + m0 + r) * 128 + nb + nt * 16 + cc]);
      hp1[nt][r] = bf2f(hst[131072 + (size_t)(b0 + m0 + r) * 128 + nb + nt * 16 + cc]);
    }
  const u16* pL = phi + (size_t)(b0 + row) * Tc * 128 + k0;
  u16* Hp = Hs + (size_t)(b0 + row) * Tc * 128 + k0;
  *(uint4*)(&pbA[0][row * 136 + k0]) = *(const uint4*)(pL);
  *(uint4*)(&pbA[1][row * 136 + k0]) = *(const uint4*)(pL + 128);
  uint4 pfA = *(const uint4*)(pL + 2 * 128);
  uint4 pfB = *(const uint4*)(pL + 3 * 128);
  __syncthreads();

  auto ITER = [&](int i, int P, int q, uint4& pf){
    short8 a0[4];
    #pragma unroll
    for (int ks = 0; ks < 4; ks++) a0[ks] = frag_ld(h0sA[P] + ks * 32, 136);
    if (i > 0){
      short8 a1[4];
      #pragma unroll
      for (int ks = 0; ks < 4; ks++) a1[ks] = frag_ld(h1sA[P ^ 1] + ks * 32, 136);
      *(uint4*)(Hp + (size_t)(i - 1) * 128) = *(const uint4*)(&h1sA[P ^ 1][row * 136 + k0]);
      f32x4 cr[2], cz[2], cin[2], chn[2];
      #pragma unroll
      for (int nt = 0; nt < 2; nt++){ cr[nt]=zero4(); cz[nt]=zero4(); cin[nt]=zero4(); chn[nt]=zero4(); }
      #pragma unroll
      for (int ks = 0; ks < 4; ks++)
        #pragma unroll
        for (int nt = 0; nt < 2; nt++){
          cr[nt]  = mfma16(a0[ks], Wr[1][0][nt][ks], cr[nt]);
          cr[nt]  = mfma16(a1[ks], Wr[2][0][nt][ks], cr[nt]);
          cz[nt]  = mfma16(a0[ks], Wr[1][1][nt][ks], cz[nt]);
          cz[nt]  = mfma16(a1[ks], Wr[2][1][nt][ks], cz[nt]);
          cin[nt] = mfma16(a0[ks], Wr[1][2][nt][ks], cin[nt]);
          chn[nt] = mfma16(a1[ks], Wr[2][2][nt][ks], chn[nt]);
        }
      #pragma unroll
      for (int nt = 0; nt < 2; nt++)
        #pragma unroll
        for (int r = 0; r < 4; r++){
          float rg = fast_sigm(cr[nt][r]);
          float zg = fast_sigm(cz[nt][r]);
          float ng = fast_tanh(cin[nt][r] + rg * chn[nt][r]);
          float hv = zg * (hp1[nt][r] - ng) + ng;
          hp1[nt][r] = hv;
          h1sA[P][(m0 + r) * 136 + nb + nt * 16 + cc] = f2bf1(hv);
        }
    }
    if (i < Tc){
      short8 ap[4];
      #pragma unroll
      for (int ks = 0; ks < 4; ks++) ap[ks] = frag_ld(pbA[q] + ks * 32, 136);
      f32x4 cr[2], cz[2], cin[2], chn[2];
      #pragma unroll
      for (int nt = 0; nt < 2; nt++){ cr[nt]=zero4(); cz[nt]=zero4(); cin[nt]=zero4(); chn[nt]=zero4(); }
      #pragma unroll
      for (int ks = 0; ks < 4; ks++)
        #pragma unroll
        for (int nt = 0; nt < 2; nt++){
          cr[nt]  = mfma16(ap[ks], frag_ld(wi0 + (0 * 128 + nb + nt * 16) * 136 + ks * 32, 136), cr[nt]);
          cr[nt]  = mfma16(a0[ks], Wr[0][0][nt][ks], cr[nt]);
          cz[nt]  = mfma16(ap[ks], frag_ld(wi0 + (1 * 128 + nb + nt * 16) * 136 + ks * 32, 136), cz[nt]);
          cz[nt]  = mfma16(a0[ks], Wr[0][1][nt][ks], cz[nt]);
          cin[nt] = mfma16(ap[ks], frag_ld(wi0 + (2 * 128 + nb + nt * 16) * 136 + ks * 32, 136), cin[nt]);
          chn[nt] = mfma16(a0[ks], Wr[0][2][nt][ks], chn[nt]);
        }
      if (i + 2 < Tc) *(uint4*)(&pbA[(q + 2) & 3][row * 136 + k0]) = pf;
      if (i + 4 < Tc) pf = *(const uint4*)(pL + (size_t)(i + 4) * 128);
      #pragma unroll
      for (int nt = 0; nt < 2; nt++)
        #pragma unroll
        for (int r = 0; r < 4; r++){
          float rg = fast_sigm(cr[nt][r]);
          float zg = fast_sigm(cz[nt][r]);
          float ng = fast_tanh(cin[nt][r] + rg * chn[nt][r]);
          float hv = zg * (hp0[nt][r] - ng) + ng;
          hp0[nt][r] = hv;
          h0sA[P ^ 1][(m0 + r) * 136 + nb + nt * 16 + cc] = f2bf1(hv);
        }
    }
    __builtin_amdgcn_sched_barrier(0);
    asm volatile("s_waitcnt lgkmcnt(0)");
    __builtin_amdgcn_s_barrier();
    __builtin_amdgcn_sched_barrier(0);
  };

  for (int i = 0; i < Tc; i += 4){
    ITER(i + 0, 0, 0, pfA);
    ITER(i + 1, 1, 1, pfB);
    ITER(i + 2, 0, 2, pfA);
    ITER(i + 3, 1, 3, pfB);
  }
  ITER(Tc, 0, 0, pfA);
  *(uint4*)(hst + (size_t)(b0 + row) * 128 + k0) = *(const uint4*)(&h0sA[0][row * 136 + k0]);
  *(uint4*)(hst + 131072 + (size_t)(b0 + row) * 128 + k0) = *(const uint4*)(&h1sA[0][row * 136 + k0]);
}

// ---- c1: 4 waves, 112 blocks ----
DEVINL void c1_body(u16* smem, int idx, const u16* phiC, const u16* HsC,
    const float* dw0, const float* db0, const float* dw1, const float* db1,
    const float* xmw, const float* xmb, const float* xlw, const float* xlb,
    u16* xmlv, int Tc){
  u16* w0s = smem;             // 33792
  u16* w1s = smem + 33792;     // 17408
  u16* xws = smem + 51200;     // 4352
  u16* buf = smem + 55552;     // 4*2176
  stage_weights(w0s, dw0, 128, 256, 256);
  stage_weights(w1s, dw1, 128, 128, 128);
  stage_weights(xws, xmw, 16, 128, 128);
  stage_weights(xws + 16 * 136, xlw, 16, 128, 128);
  int wv = threadIdx.x >> 6, l = threadIdx.x & 63;
  u16* mybuf = buf + wv * 2176;
  float b0v[8], b1v[8];
  #pragma unroll
  for (int nt = 0; nt < 8; nt++){
    b0v[nt] = db0[nt * 16 + (l & 15)];
    b1v[nt] = db1[nt * 16 + (l & 15)];
  }
  float bxm = xmb[l & 15], bxl = xlb[l & 15];
  __syncthreads();
  int tpb = Tc >> 4;
  int ntile = 1024 * tpb;
  for (int tile = idx * 4 + wv; tile < ntile; tile += 112 * 4){
    int b = tile / tpb;
    int tt = (tile - b * tpb) << 4;
    size_t rbase = (size_t)(b * Tc + tt);
    const u16* ap = phiC + rbase * 128;
    const u16* hp = HsC + rbase * 128;
    f32x4 acc[8];
    #pragma unroll
    for (int nt = 0; nt < 8; nt++) acc[nt] = zero4();
    #pragma unroll
    for (int ks = 0; ks < 8; ks++){
      short8 a = (ks < 4) ? gfrag(ap, 128, ks) : gfrag(hp, 128, ks - 4);
      #pragma unroll
      for (int nt = 0; nt < 8; nt++)
        acc[nt] = mfma16(a, frag_ld(w0s + nt * 16 * 264 + ks * 32, 264), acc[nt]);
    }
    #pragma unroll
    for (int nt = 0; nt < 8; nt++)
      acc_store_lds(mybuf, 136, nt * 16, acc[nt], b0v[nt], true);
    f32x4 a2[8];
    #pragma unroll
    for (int nt = 0; nt < 8; nt++) a2[nt] = zero4();
    #pragma unroll
    for (int ks = 0; ks < 4; ks++){
      short8 a = frag_ld(mybuf + ks * 32, 136);
      #pragma unroll
      for (int nt = 0; nt < 8; nt++)
        a2[nt] = mfma16(a, frag_ld(w1s + nt * 16 * 136 + ks * 32, 136), a2[nt]);
    }
    #pragma unroll
    for (int nt = 0; nt < 8; nt++)
      acc_store_lds(mybuf, 136, nt * 16, a2[nt], b1v[nt], false);
    f32x4 am = zero4(), al = zero4();
    #pragma unroll
    for (int ks = 0; ks < 4; ks++){
      short8 a = frag_ld(mybuf + ks * 32, 136);
      am = mfma16(a, frag_ld(xws + ks * 32, 136), am);
      al = mfma16(a, frag_ld(xws + 16 * 136 + ks * 32, 136), al);
    }
    acc_store_lds(mybuf, 136, 0, am, bxm, false);
    acc_store_lds(mybuf, 136, 16, al, bxl, false);
    u16* dst = xmlv + rbase * 32;
    int c = l;
    int row = c >> 2, k = (c & 3) * 8;
    *(short8*)(dst + row * 32 + k) = *(const short8*)(mybuf + row * 136 + k);
  }
}

// ---- c2: 4 waves, 112 blocks ----
DEVINL void c2_body(u16* smem, int idx, const u16* xmlv, const float* y,
    const float* pw0, const float* pb0, const float* pw1, const float* pb1,
    const float* mw0, const float* mb0, const float* mw1, const float* mb1,
    const float* Cw, float* out, int t0, int Tc){
  u16* pw0s = smem;            // 5120
  u16* pw1s = smem + 5120;     // 17408
  u16* mw0s = smem + 22528;    // 17408
  u16* mw1s = smem + 39936;    // 2176
  u16* Cs   = smem + 42112;    // 640
  u16* buf  = smem + 42752;    // 4*2176
  stage_weights(pw0s, pw0, 128, 32, 32);
  stage_weights(pw1s, pw1, 128, 128, 128);
  stage_weights(mw0s, mw0, 128, 128, 128);
  stage_weights(mw1s, mw1, 16, 128, 128);
  stage_weights(Cs, Cw, 16, 16, 32);
  int wv = threadIdx.x >> 6, l = threadIdx.x & 63;
  u16* mybuf = buf + wv * 2176;
  float bp0v[8], bp1v[8], bm0v[8];
  #pragma unroll
  for (int nt = 0; nt < 8; nt++){
    bp0v[nt] = pb0[nt * 16 + (l & 15)];
    bp1v[nt] = pb1[nt * 16 + (l & 15)];
    bm0v[nt] = mb0[nt * 16 + (l & 15)];
  }
  float bm1 = mb1[l & 15];
  __syncthreads();
  float lacc = 0.f;
  int tpb = Tc >> 4;
  int ntile = 1024 * tpb;
  for (int tile = idx * 4 + wv; tile < ntile; tile += 112 * 4){
    int b = tile / tpb;
    int tt = (tile - b * tpb) << 4;
    size_t rbase = (size_t)(b * Tc + tt);
    const u16* xp = xmlv + rbase * 32;
    short8 a0 = gfrag(xp, 32, 0);
    f32x4 acc[8];
    #pragma unroll
    for (int nt = 0; nt < 8; nt++)
      acc[nt] = mfma16(a0, frag_ld(pw0s + nt * 16 * 40, 40), zero4());
    #pragma unroll
    for (int nt = 0; nt < 8; nt++)
      acc_store_lds(mybuf, 136, nt * 16, acc[nt], bp0v[nt], true);
    f32x4 a2[8];
    #pragma unroll
    for (int nt = 0; nt < 8; nt++) a2[nt] = zero4();
    #pragma unroll
    for (int ks = 0; ks < 4; ks++){
      short8 a = frag_ld(mybuf + ks * 32, 136);
      #pragma unroll
      for (int nt = 0; nt < 8; nt++)
        a2[nt] = mfma16(a, frag_ld(pw1s + nt * 16 * 136 + ks * 32, 136), a2[nt]);
    }
    #pragma unroll
    for (int nt = 0; nt < 8; nt++)
      acc_store_lds(mybuf, 136, nt * 16, a2[nt], bp1v[nt], false);
    f32x4 a3[8];
    #pragma unroll
    for (int nt = 0; nt < 8; nt++) a3[nt] = zero4();
    #pragma unroll
    for (int ks = 0; ks < 4; ks++){
      short8 a = frag_ld(mybuf + ks * 32, 136);
      #pragma unroll
      for (int nt = 0; nt < 8; nt++)
        a3[nt] = mfma16(a, frag_ld(mw0s + nt * 16 * 136 + ks * 32, 136), a3[nt]);
    }
    #pragma unroll
    for (int nt = 0; nt < 8; nt++)
      acc_store_lds(mybuf, 136, nt * 16, a3[nt], bm0v[nt], true);
    f32x4 ay = zero4();
    #pragma unroll
    for (int ks = 0; ks < 4; ks++){
      short8 a = frag_ld(mybuf + ks * 32, 136);
      ay = mfma16(a, frag_ld(mw1s + ks * 32, 136), ay);
    }
    f32x4 ac = mfma16(a0, frag_ld(Cs, 40), zero4());
    #pragma unroll
    for (int r = 0; r < 4; r++){
      float yh = ay[r] + bm1 + ac[r];
      int m = (l >> 4) * 4 + r, j = l & 15;
      float d = yh - y[(size_t)(b * 16 + j) * 1024 + t0 + tt + m];
      lacc += d * d;
    }
  }
  #pragma unroll
  for (int off = 32; off > 0; off >>= 1)
    lacc += __shfl_down(lacc, off);
  if (l == 0) atomicAdd(out, lacc);
}

// ================= fused pipeline kernel =================
// launch j: phiu(j) | gru(j-1) | c1(j-2) | c2(j-3).
// XCD partition (256-thread blocks, VGPR 256 preserved): gru on bi%8 in {0,1}
// (XCD 0-1 under round-robin); workers (112/role) on bi%8 in {2..7}.
__global__ __launch_bounds__(256, 1) void k_fused(
    const float* __restrict__ u, const float* __restrict__ y,
    const float* puw0, const float* pub0, const float* puw1, const float* pub1,
    const float* dw0, const float* db0, const float* dw1, const float* db1,
    const float* xmw, const float* xmb, const float* xlw, const float* xlb,
    const float* pxw0, const float* pxb0, const float* pxw1, const float* pxb1,
    const float* mw0, const float* mb0, const float* mw1, const float* mb1,
    const float* Cw, const float* gwih, const float* gwhh,
    u16* phiW, const u16* phiG, const u16* phiC,
    u16* hst, u16* HsW, const u16* HsC,
    u16* xmW, const u16* xmC,
    float* out, int t0phiu, int t0c2, int Tc, int flags){
  __shared__ __align__(16) u16 smem[69632];   // 139264 B arena, unioned across roles
  int bi = blockIdx.x;
  int lane8 = bi & 7;
  if (lane8 < 2){
    int gidx = (bi >> 3) * 2 + lane8;
    if (gidx < 64 && (flags & 2))
      gru_body(smem, gidx, phiG, gwih, gwhh, hst, HsW, Tc);
    return;
  }
  int w = (bi >> 3) * 6 + (lane8 - 2);   // 0..335
  int role = w / 112, idx = w - role * 112;
  if (role == 0){
    if (flags & 1) phiu_body(smem, idx, u, puw0, pub0, puw1, pub1, phiW, t0phiu, Tc);
  } else if (role == 1){
    if (flags & 4) c1_body(smem, idx, phiC, HsC, dw0, db0, dw1, db1, xmw, xmb, xlw, xlb, xmW, Tc);
  } else {
    if (flags & 8) c2_body(smem, idx, xmC, y, pxw0, pxb0, pxw1, pxb1, mw0, mb0, mw1, mb1, Cw, out, t0c2, Tc);
  }
}

extern "C" void kernel_launch(void* const* d_in, const int* in_sizes, int n_in,
                              void* d_out, int out_size, void* d_ws, size_t ws_size,
                              hipStream_t stream){
  const float* u    = (const float*)d_in[0];
  const float* y    = (const float*)d_in[1];
  const float* h0   = (const float*)d_in[2];
  const float* puw0 = (const float*)d_in[3];
  const float* pub0 = (const float*)d_in[4];
  const float* puw1 = (const float*)d_in[5];
  const float* pub1 = (const float*)d_in[6];
  const float* dw0  = (const float*)d_in[7];
  const float* db0  = (const float*)d_in[8];
  const float* dw1  = (const float*)d_in[9];
  const float* db1  = (const float*)d_in[10];
  const float* xmw  = (const float*)d_in[11];
  const float* xmb  = (const float*)d_in[12];
  const float* xlw  = (const float*)d_in[13];
  const float* xlb  = (const float*)d_in[14];
  const float* pxw0 = (const float*)d_in[15];
  const float* pxb0 = (const float*)d_in[16];
  const float* pxw1 = (const float*)d_in[17];
  const float* pxb1 = (const float*)d_in[18];
  const float* mw0  = (const float*)d_in[19];
  const float* mb0  = (const float*)d_in[20];
  const float* mw1  = (const float*)d_in[21];
  const float* mb1  = (const float*)d_in[22];
  const float* gwih = (const float*)d_in[23];
  const float* gwhh = (const float*)d_in[24];
  const float* Cw   = (const float*)d_in[25];

  const size_t hstE = (size_t)2 * 1024 * 128;
  int Tc = 128;
  while (Tc > 16){
    size_t needB = (hstE + (size_t)1024 * Tc * (3 * 128 + 2 * 128 + 2 * 32)) * 2 + 4096;
    if (needB <= ws_size) break;
    Tc >>= 1;
  }
  int NC = 1024 / Tc;
  size_t phiSz = (size_t)1024 * Tc * 128;   // elems; Hs slot same size
  size_t xmSz  = (size_t)1024 * Tc * 32;

  u16* hst  = (u16*)d_ws;
  u16* phiB = hst + hstE;
  u16* HsB  = phiB + 3 * phiSz;
  u16* xmB  = HsB + 2 * phiSz;

  hipMemsetAsync(d_out, 0, sizeof(float), stream);
  k_inith<<<1024, 256, 0, stream>>>(h0, hst);

  for (int j = 0; j <= NC + 2; j++){
    int flags = 0;
    if (j < NC) flags |= 1;                    // phiu(j)
    if (j >= 1 && j <= NC) flags |= 2;         // gru(j-1)
    if (j >= 2 && j <= NC + 1) flags |= 4;     // c1(j-2)
    if (j >= 3) flags |= 8;                    // c2(j-3)
    int s0 = j % 3, s1 = (j + 2) % 3, s2 = (j + 1) % 3;
    int hw = (j + 1) & 1, hc = j & 1;
    int xw = j & 1, xc = (j + 1) & 1;
    k_fused<<<448, 256, 0, stream>>>(
        u, y,
        puw0, pub0, puw1, pub1,
        dw0, db0, dw1, db1, xmw, xmb, xlw, xlb,
        pxw0, pxb0, pxw1, pxb1, mw0, mb0, mw1, mb1,
        Cw, gwih, gwhh,
        phiB + (size_t)s0 * phiSz, phiB + (size_t)s1 * phiSz, phiB + (size_t)s2 * phiSz,
        hst, HsB + (size_t)hw * phiSz, HsB + (size_t)hc * phiSz,
        xmB + (size_t)xw * xmSz, xmB + (size_t)xc * xmSz,
        (float*)d_out, j * Tc, (j - 3) * Tc, Tc, flags);
  }
}

// Round 15
// 2764.005 us; speedup vs baseline: 5.7309x; 1.2150x over previous
//
#include <hip/hip_runtime.h>
#include <hip/hip_bf16.h>

typedef unsigned short u16;
typedef unsigned int u32;
using short8 = __attribute__((ext_vector_type(8))) short;
using f32x4  = __attribute__((ext_vector_type(4))) float;

#define DEVINL static __device__ __forceinline__

DEVINL float bf2f(u16 u){
  union { unsigned int i; float f; } x; x.i = ((unsigned int)u) << 16; return x.f;
}
DEVINL u16 f2bf(float f){
  union { float f; unsigned int i; } x; x.f = f;
  unsigned int i = x.i;
  return (u16)((i + 0x7FFFu + ((i >> 16) & 1u)) >> 16);
}
DEVINL u16 f2bf1(float f){
  __hip_bfloat16 b = __float2bfloat16(f);
  u16 u; __builtin_memcpy(&u, &b, 2); return u;
}
DEVINL float fast_sigm(float x){
  float e = __builtin_amdgcn_exp2f(x * -1.442695041f);
  return __builtin_amdgcn_rcpf(1.f + e);
}
DEVINL float fast_tanh(float x){
  x = fminf(fmaxf(x, -10.f), 10.f);
  float e = __builtin_amdgcn_exp2f(x * -2.885390082f);
  return (1.f - e) * __builtin_amdgcn_rcpf(1.f + e);
}
DEVINL f32x4 zero4(){ f32x4 z = {0.f, 0.f, 0.f, 0.f}; return z; }

DEVINL f32x4 mfma16(short8 a, short8 b, f32x4 c){
  return __builtin_amdgcn_mfma_f32_16x16x32_bf16(a, b, c, 0, 0, 0);
}

// lane l: row = l&15, k0 = (l>>4)*8 ; 16B vector read. stride in u16 elements
DEVINL short8 frag_ld(const u16* base, int stride){
  int l = threadIdx.x & 63;
  return *(const short8*)(base + (l & 15) * stride + ((l >> 4) << 3));
}
DEVINL short8 gfrag(const u16* rowbase, int stride, int ks){
  int l = threadIdx.x & 63;
  return *(const short8*)(rowbase + (size_t)(l & 15) * stride + ks * 32 + ((l >> 4) << 3));
}

DEVINL void acc_store_lds(u16* dst, int stride, int col_base, f32x4 acc, float bias, bool relu){
  int l = threadIdx.x & 63;
  int col = col_base + (l & 15);
  int row0 = (l >> 4) * 4;
  #pragma unroll
  for (int r = 0; r < 4; r++){
    float v = acc[r] + bias;
    if (relu) v = fmaxf(v, 0.f);
    dst[(row0 + r) * stride + col] = f2bf(v);
  }
}

DEVINL void stage_weights(u16* dst, const float* src, int N, int K, int Kp){
  int stride = Kp + 8;
  if (Kp > K){
    int padw = Kp - K;
    for (int i = threadIdx.x; i < N * padw; i += blockDim.x){
      int n = i / padw, k = K + (i - (i / padw) * padw);
      dst[n * stride + k] = 0;
    }
  }
  for (int i = threadIdx.x * 4; i < N * K; i += blockDim.x * 4){
    float4 v = *(const float4*)(src + i);
    int n = i / K, k = i - n * K;
    u16* d = dst + n * stride + k;
    d[0] = f2bf(v.x); d[1] = f2bf(v.y); d[2] = f2bf(v.z); d[3] = f2bf(v.w);
  }
}

__global__ __launch_bounds__(256) void k_inith(const float* __restrict__ h0, u16* __restrict__ hst){
  int i = blockIdx.x * 256 + threadIdx.x;
  if (i < 2 * 1024 * 128) hst[i] = f2bf(h0[i]);
}

// ================= role bodies (shared smem arena; idx = role-local block index) ==========

// ---- phi_u: 8 waves ----
DEVINL void phiu_body(u16* smem, int idx, int rs, const float* u, const float* w0, const float* b0,
                      const float* w1, const float* b1, u16* phiW, int t0, int Tc){
  u16* w0s = smem;              // 5120
  u16* w1s = smem + 5120;       // 17408
  u16* buf = smem + 22528;      // 8 * 2176
  stage_weights(w0s, w0, 128, 16, 32);
  stage_weights(w1s, w1, 128, 128, 128);
  int wv = threadIdx.x >> 6, l = threadIdx.x & 63;
  u16* mybuf = buf + wv * 2176;
  float b0v[8], b1v[8];
  #pragma unroll
  for (int nt = 0; nt < 8; nt++){
    b0v[nt] = b0[nt * 16 + (l & 15)];
    b1v[nt] = b1[nt * 16 + (l & 15)];
  }
  __syncthreads();
  int tpb = Tc >> 4;
  int ntile = 1024 * tpb;
  for (int tile = idx * 8 + wv; tile < ntile; tile += rs * 8){
    int b = tile / tpb;
    int tt = (tile - b * tpb) << 4;
    int t = l & 15, kb = l >> 4;
    #pragma unroll
    for (int j = 0; j < 4; j++){
      int k = kb + j * 4;
      mybuf[t * 136 + k] = f2bf(u[(size_t)(b * 16 + k) * 1024 + t0 + tt + t]);
      mybuf[t * 136 + 16 + k] = 0;
    }
    short8 a0 = frag_ld(mybuf, 136);
    f32x4 acc[8];
    #pragma unroll
    for (int nt = 0; nt < 8; nt++)
      acc[nt] = mfma16(a0, frag_ld(w0s + nt * 16 * 40, 40), zero4());
    #pragma unroll
    for (int nt = 0; nt < 8; nt++)
      acc_store_lds(mybuf, 136, nt * 16, acc[nt], b0v[nt], true);
    f32x4 a2[8];
    #pragma unroll
    for (int nt = 0; nt < 8; nt++) a2[nt] = zero4();
    #pragma unroll
    for (int ks = 0; ks < 4; ks++){
      short8 a = frag_ld(mybuf + ks * 32, 136);
      #pragma unroll
      for (int nt = 0; nt < 8; nt++)
        a2[nt] = mfma16(a, frag_ld(w1s + nt * 16 * 136 + ks * 32, 136), a2[nt]);
    }
    #pragma unroll
    for (int nt = 0; nt < 8; nt++)
      acc_store_lds(mybuf, 136, nt * 16, a2[nt], b1v[nt], false);
    u16* dst = phiW + (size_t)(b * Tc + tt) * 128;
    #pragma unroll
    for (int j = 0; j < 4; j++){
      int c = j * 64 + l;
      int row = c >> 4, k = (c & 15) * 8;
      *(short8*)(dst + row * 128 + k) = *(const short8*)(mybuf + row * 136 + k);
    }
  }
}

// ---- GRU: r7 8-wave body (VGPR-light: weights in W[4][3][4] -> AGPRs), 64 blocks ----
DEVINL void gru_body(u16* smem, int idx, const u16* __restrict__ phi,
                     const float* gwih, const float* gwhh,
                     u16* hst, u16* Hs, int Tc){
  u16* h0sA[2] = { smem,        smem + 2176 };
  u16* h1sA[2] = { smem + 4352, smem + 6528 };
  u16* pbA[4]  = { smem + 8704, smem + 10880, smem + 13056, smem + 15232 };
  const int l = threadIdx.x & 63;
  const int wv = threadIdx.x >> 6;      // 0..7, wave owns 16 neurons
  const int b0 = idx * 16;
  const int m0 = (l >> 4) * 4;
  const int colw = wv * 16 + (l & 15);

  // W[0]=wih0, W[1]=whh0, W[2]=wih1, W[3]=whh1 ; 12 short8 each (48 VGPR-equiv, AGPR-resident)
  const float* srcs[4] = { gwih, gwhh, gwih + 49152, gwhh + 49152 };
  short8 W[4][3][4];
  #pragma unroll
  for (int mm = 0; mm < 4; mm++){
    #pragma unroll
    for (int g = 0; g < 3; g++){
      int n = g * 128 + colw;
      #pragma unroll
      for (int ks = 0; ks < 4; ks++){
        const float* p = srcs[mm] + (size_t)n * 128 + ks * 32 + ((l >> 4) << 3);
        float4 va = *(const float4*)p;
        float4 vb = *(const float4*)(p + 4);
        short8 f;
        f[0] = (short)f2bf(va.x); f[1] = (short)f2bf(va.y);
        f[2] = (short)f2bf(va.z); f[3] = (short)f2bf(va.w);
        f[4] = (short)f2bf(vb.x); f[5] = (short)f2bf(vb.y);
        f[6] = (short)f2bf(vb.z); f[7] = (short)f2bf(vb.w);
        W[mm][g][ks] = f;
      }
    }
  }
  const int row = threadIdx.x >> 5, k0 = (threadIdx.x & 31) * 4;   // 512 thr x 8B
  *(uint2*)(&h0sA[0][row * 136 + k0]) = *(const uint2*)(hst + (size_t)(b0 + row) * 128 + k0);
  *(uint2*)(&h1sA[0][row * 136 + k0]) = *(const uint2*)(hst + 131072 + (size_t)(b0 + row) * 128 + k0);
  float hp0[4], hp1[4];
  #pragma unroll
  for (int r = 0; r < 4; r++){
    hp0[r] = bf2f(hst[(size_t)(b0 + m0 + r) * 128 + colw]);
    hp1[r] = bf2f(hst[131072 + (size_t)(b0 + m0 + r) * 128 + colw]);
  }
  const u16* pL = phi + (size_t)(b0 + row) * Tc * 128 + k0;
  u16* Hp = Hs + (size_t)(b0 + row) * Tc * 128 + k0;
  *(uint2*)(&pbA[0][row * 136 + k0]) = *(const uint2*)(pL);
  *(uint2*)(&pbA[1][row * 136 + k0]) = *(const uint2*)(pL + 128);
  uint2 pfA = *(const uint2*)(pL + 2 * 128);
  uint2 pfB = *(const uint2*)(pL + 3 * 128);
  __syncthreads();

  // ITER(i): layer1 completes GRU step i-1; layer0 computes H0[i+1]=f(H0[i],phi(i)).
  auto ITER = [&](int i, int P, int q, uint2& pf){
    short8 a0[4];
    #pragma unroll
    for (int ks = 0; ks < 4; ks++) a0[ks] = frag_ld(h0sA[P] + ks * 32, 136);
    if (i > 0){
      short8 a1[4];
      #pragma unroll
      for (int ks = 0; ks < 4; ks++) a1[ks] = frag_ld(h1sA[P ^ 1] + ks * 32, 136);
      *(uint2*)(Hp + (size_t)(i - 1) * 128) = *(const uint2*)(&h1sA[P ^ 1][row * 136 + k0]);
      f32x4 xr = zero4(), xz = zero4(), xn = zero4();
      f32x4 hr = zero4(), hz = zero4(), hh = zero4();
      #pragma unroll
      for (int ks = 0; ks < 4; ks++){
        xr = mfma16(a0[ks], W[2][0][ks], xr);
        xz = mfma16(a0[ks], W[2][1][ks], xz);
        xn = mfma16(a0[ks], W[2][2][ks], xn);
        hr = mfma16(a1[ks], W[3][0][ks], hr);
        hz = mfma16(a1[ks], W[3][1][ks], hz);
        hh = mfma16(a1[ks], W[3][2][ks], hh);
      }
      #pragma unroll
      for (int r = 0; r < 4; r++){
        float rg = fast_sigm(xr[r] + hr[r]);
        float zg = fast_sigm(xz[r] + hz[r]);
        float ng = fast_tanh(xn[r] + rg * hh[r]);
        float hv = zg * (hp1[r] - ng) + ng;
        hp1[r] = hv;
        h1sA[P][(m0 + r) * 136 + colw] = f2bf1(hv);
      }
    }
    if (i < Tc){
      short8 ap[4];
      #pragma unroll
      for (int ks = 0; ks < 4; ks++) ap[ks] = frag_ld(pbA[q] + ks * 32, 136);
      f32x4 xr = zero4(), xz = zero4(), xn = zero4();
      f32x4 hr = zero4(), hz = zero4(), hh = zero4();
      #pragma unroll
      for (int ks = 0; ks < 4; ks++){
        xr = mfma16(ap[ks], W[0][0][ks], xr);
        xz = mfma16(ap[ks], W[0][1][ks], xz);
        xn = mfma16(ap[ks], W[0][2][ks], xn);
        hr = mfma16(a0[ks], W[1][0][ks], hr);
        hz = mfma16(a0[ks], W[1][1][ks], hz);
        hh = mfma16(a0[ks], W[1][2][ks], hh);
      }
      if (i + 2 < Tc) *(uint2*)(&pbA[(q + 2) & 3][row * 136 + k0]) = pf;
      if (i + 4 < Tc) pf = *(const uint2*)(pL + (size_t)(i + 4) * 128);
      #pragma unroll
      for (int r = 0; r < 4; r++){
        float rg = fast_sigm(xr[r] + hr[r]);
        float zg = fast_sigm(xz[r] + hz[r]);
        float ng = fast_tanh(xn[r] + rg * hh[r]);
        float hv = zg * (hp0[r] - ng) + ng;
        hp0[r] = hv;
        h0sA[P ^ 1][(m0 + r) * 136 + colw] = f2bf1(hv);
      }
    }
    __builtin_amdgcn_sched_barrier(0);
    asm volatile("s_waitcnt lgkmcnt(0)");
    __builtin_amdgcn_s_barrier();
    __builtin_amdgcn_sched_barrier(0);
  };

  for (int i = 0; i < Tc; i += 4){
    ITER(i + 0, 0, 0, pfA);
    ITER(i + 1, 1, 1, pfB);
    ITER(i + 2, 0, 2, pfA);
    ITER(i + 3, 1, 3, pfB);
  }
  ITER(Tc, 0, 0, pfA);
  *(uint2*)(hst + (size_t)(b0 + row) * 128 + k0) = *(const uint2*)(&h0sA[0][row * 136 + k0]);
  *(uint2*)(hst + 131072 + (size_t)(b0 + row) * 128 + k0) = *(const uint2*)(&h1sA[0][row * 136 + k0]);
}

// ---- c1: 8 waves ----
DEVINL void c1_body(u16* smem, int idx, int rs, const u16* phiC, const u16* HsC,
    const float* dw0, const float* db0, const float* dw1, const float* db1,
    const float* xmw, const float* xmb, const float* xlw, const float* xlb,
    u16* xmlv, int Tc){
  u16* w0s = smem;             // 33792
  u16* w1s = smem + 33792;     // 17408
  u16* xws = smem + 51200;     // 4352
  u16* buf = smem + 55552;     // 8*2176
  stage_weights(w0s, dw0, 128, 256, 256);
  stage_weights(w1s, dw1, 128, 128, 128);
  stage_weights(xws, xmw, 16, 128, 128);
  stage_weights(xws + 16 * 136, xlw, 16, 128, 128);
  int wv = threadIdx.x >> 6, l = threadIdx.x & 63;
  u16* mybuf = buf + wv * 2176;
  float b0v[8], b1v[8];
  #pragma unroll
  for (int nt = 0; nt < 8; nt++){
    b0v[nt] = db0[nt * 16 + (l & 15)];
    b1v[nt] = db1[nt * 16 + (l & 15)];
  }
  float bxm = xmb[l & 15], bxl = xlb[l & 15];
  __syncthreads();
  int tpb = Tc >> 4;
  int ntile = 1024 * tpb;
  for (int tile = idx * 8 + wv; tile < ntile; tile += rs * 8){
    int b = tile / tpb;
    int tt = (tile - b * tpb) << 4;
    size_t rbase = (size_t)(b * Tc + tt);
    const u16* ap = phiC + rbase * 128;
    const u16* hp = HsC + rbase * 128;
    f32x4 acc[8];
    #pragma unroll
    for (int nt = 0; nt < 8; nt++) acc[nt] = zero4();
    #pragma unroll
    for (int ks = 0; ks < 8; ks++){
      short8 a = (ks < 4) ? gfrag(ap, 128, ks) : gfrag(hp, 128, ks - 4);
      #pragma unroll
      for (int nt = 0; nt < 8; nt++)
        acc[nt] = mfma16(a, frag_ld(w0s + nt * 16 * 264 + ks * 32, 264), acc[nt]);
    }
    #pragma unroll
    for (int nt = 0; nt < 8; nt++)
      acc_store_lds(mybuf, 136, nt * 16, acc[nt], b0v[nt], true);
    f32x4 a2[8];
    #pragma unroll
    for (int nt = 0; nt < 8; nt++) a2[nt] = zero4();
    #pragma unroll
    for (int ks = 0; ks < 4; ks++){
      short8 a = frag_ld(mybuf + ks * 32, 136);
      #pragma unroll
      for (int nt = 0; nt < 8; nt++)
        a2[nt] = mfma16(a, frag_ld(w1s + nt * 16 * 136 + ks * 32, 136), a2[nt]);
    }
    #pragma unroll
    for (int nt = 0; nt < 8; nt++)
      acc_store_lds(mybuf, 136, nt * 16, a2[nt], b1v[nt], false);
    f32x4 am = zero4(), al = zero4();
    #pragma unroll
    for (int ks = 0; ks < 4; ks++){
      short8 a = frag_ld(mybuf + ks * 32, 136);
      am = mfma16(a, frag_ld(xws + ks * 32, 136), am);
      al = mfma16(a, frag_ld(xws + 16 * 136 + ks * 32, 136), al);
    }
    acc_store_lds(mybuf, 136, 0, am, bxm, false);
    acc_store_lds(mybuf, 136, 16, al, bxl, false);
    u16* dst = xmlv + rbase * 32;
    int c = l;
    int row = c >> 2, k = (c & 3) * 8;
    *(short8*)(dst + row * 32 + k) = *(const short8*)(mybuf + row * 136 + k);
  }
}

// ---- c2: 8 waves ----
DEVINL void c2_body(u16* smem, int idx, int rs, const u16* xmlv, const float* y,
    const float* pw0, const float* pb0, const float* pw1, const float* pb1,
    const float* mw0, const float* mb0, const float* mw1, const float* mb1,
    const float* Cw, float* out, int t0, int Tc){
  u16* pw0s = smem;            // 5120
  u16* pw1s = smem + 5120;     // 17408
  u16* mw0s = smem + 22528;    // 17408
  u16* mw1s = smem + 39936;    // 2176
  u16* Cs   = smem + 42112;    // 640
  u16* buf  = smem + 42752;    // 8*2176
  stage_weights(pw0s, pw0, 128, 32, 32);
  stage_weights(pw1s, pw1, 128, 128, 128);
  stage_weights(mw0s, mw0, 128, 128, 128);
  stage_weights(mw1s, mw1, 16, 128, 128);
  stage_weights(Cs, Cw, 16, 16, 32);
  int wv = threadIdx.x >> 6, l = threadIdx.x & 63;
  u16* mybuf = buf + wv * 2176;
  float bp0v[8], bp1v[8], bm0v[8];
  #pragma unroll
  for (int nt = 0; nt < 8; nt++){
    bp0v[nt] = pb0[nt * 16 + (l & 15)];
    bp1v[nt] = pb1[nt * 16 + (l & 15)];
    bm0v[nt] = mb0[nt * 16 + (l & 15)];
  }
  float bm1 = mb1[l & 15];
  __syncthreads();
  float lacc = 0.f;
  int tpb = Tc >> 4;
  int ntile = 1024 * tpb;
  for (int tile = idx * 8 + wv; tile < ntile; tile += rs * 8){
    int b = tile / tpb;
    int tt = (tile - b * tpb) << 4;
    size_t rbase = (size_t)(b * Tc + tt);
    const u16* xp = xmlv + rbase * 32;
    short8 a0 = gfrag(xp, 32, 0);
    f32x4 acc[8];
    #pragma unroll
    for (int nt = 0; nt < 8; nt++)
      acc[nt] = mfma16(a0, frag_ld(pw0s + nt * 16 * 40, 40), zero4());
    #pragma unroll
    for (int nt = 0; nt < 8; nt++)
      acc_store_lds(mybuf, 136, nt * 16, acc[nt], bp0v[nt], true);
    f32x4 a2[8];
    #pragma unroll
    for (int nt = 0; nt < 8; nt++) a2[nt] = zero4();
    #pragma unroll
    for (int ks = 0; ks < 4; ks++){
      short8 a = frag_ld(mybuf + ks * 32, 136);
      #pragma unroll
      for (int nt = 0; nt < 8; nt++)
        a2[nt] = mfma16(a, frag_ld(pw1s + nt * 16 * 136 + ks * 32, 136), a2[nt]);
    }
    #pragma unroll
    for (int nt = 0; nt < 8; nt++)
      acc_store_lds(mybuf, 136, nt * 16, a2[nt], bp1v[nt], false);
    f32x4 a3[8];
    #pragma unroll
    for (int nt = 0; nt < 8; nt++) a3[nt] = zero4();
    #pragma unroll
    for (int ks = 0; ks < 4; ks++){
      short8 a = frag_ld(mybuf + ks * 32, 136);
      #pragma unroll
      for (int nt = 0; nt < 8; nt++)
        a3[nt] = mfma16(a, frag_ld(mw0s + nt * 16 * 136 + ks * 32, 136), a3[nt]);
    }
    #pragma unroll
    for (int nt = 0; nt < 8; nt++)
      acc_store_lds(mybuf, 136, nt * 16, a3[nt], bm0v[nt], true);
    f32x4 ay = zero4();
    #pragma unroll
    for (int ks = 0; ks < 4; ks++){
      short8 a = frag_ld(mybuf + ks * 32, 136);
      ay = mfma16(a, frag_ld(mw1s + ks * 32, 136), ay);
    }
    f32x4 ac = mfma16(a0, frag_ld(Cs, 40), zero4());
    #pragma unroll
    for (int r = 0; r < 4; r++){
      float yh = ay[r] + bm1 + ac[r];
      int m = (l >> 4) * 4 + r, j = l & 15;
      float d = yh - y[(size_t)(b * 16 + j) * 1024 + t0 + tt + m];
      lacc += d * d;
    }
  }
  #pragma unroll
  for (int off = 32; off > 0; off >>= 1)
    lacc += __shfl_down(lacc, off);
  if (l == 0) atomicAdd(out, lacc);
}

// ================= fused pipeline kernel (512 thr) =================
// launch j: phiu(j) | gru(j-1) | c1(j-2) | c2(j-3). gru blocks [0,64) only when active;
// worker role ranges computed from runtime base so tail launches use the whole grid.
__global__ __launch_bounds__(512, 1) void k_fused(
    const float* __restrict__ u, const float* __restrict__ y,
    const float* puw0, const float* pub0, const float* puw1, const float* pub1,
    const float* dw0, const float* db0, const float* dw1, const float* db1,
    const float* xmw, const float* xmb, const float* xlw, const float* xlb,
    const float* pxw0, const float* pxb0, const float* pxw1, const float* pxb1,
    const float* mw0, const float* mb0, const float* mw1, const float* mb1,
    const float* Cw, const float* gwih, const float* gwhh,
    u16* phiW, const u16* phiG, const u16* phiC,
    u16* hst, u16* HsW, const u16* HsC,
    u16* xmW, const u16* xmC,
    float* out, int t0phiu, int t0c2, int Tc, int flags){
  __shared__ __align__(16) u16 smem[72960];   // 145920 B arena, unioned across roles
  int bi = blockIdx.x;
  bool gruOn = (flags & 2) != 0;
  if (gruOn && bi < 64){
    gru_body(smem, bi, phiG, gwih, gwhh, hst, HsW, Tc);
    return;
  }
  int wb = gruOn ? 64 : 0;
  int w = bi - wb;
  int rs = (448 - wb) / 3;
  int role = w / rs;
  int idx = w - role * rs;
  if (role > 2) return;
  if (role == 0){
    if (flags & 1) phiu_body(smem, idx, rs, u, puw0, pub0, puw1, pub1, phiW, t0phiu, Tc);
  } else if (role == 1){
    if (flags & 4) c1_body(smem, idx, rs, phiC, HsC, dw0, db0, dw1, db1, xmw, xmb, xlw, xlb, xmW, Tc);
  } else {
    if (flags & 8) c2_body(smem, idx, rs, xmC, y, pxw0, pxb0, pxw1, pxb1, mw0, mb0, mw1, mb1, Cw, out, t0c2, Tc);
  }
}

extern "C" void kernel_launch(void* const* d_in, const int* in_sizes, int n_in,
                              void* d_out, int out_size, void* d_ws, size_t ws_size,
                              hipStream_t stream){
  const float* u    = (const float*)d_in[0];
  const float* y    = (const float*)d_in[1];
  const float* h0   = (const float*)d_in[2];
  const float* puw0 = (const float*)d_in[3];
  const float* pub0 = (const float*)d_in[4];
  const float* puw1 = (const float*)d_in[5];
  const float* pub1 = (const float*)d_in[6];
  const float* dw0  = (const float*)d_in[7];
  const float* db0  = (const float*)d_in[8];
  const float* dw1  = (const float*)d_in[9];
  const float* db1  = (const float*)d_in[10];
  const float* xmw  = (const float*)d_in[11];
  const float* xmb  = (const float*)d_in[12];
  const float* xlw  = (const float*)d_in[13];
  const float* xlb  = (const float*)d_in[14];
  const float* pxw0 = (const float*)d_in[15];
  const float* pxb0 = (const float*)d_in[16];
  const float* pxw1 = (const float*)d_in[17];
  const float* pxb1 = (const float*)d_in[18];
  const float* mw0  = (const float*)d_in[19];
  const float* mb0  = (const float*)d_in[20];
  const float* mw1  = (const float*)d_in[21];
  const float* mb1  = (const float*)d_in[22];
  const float* gwih = (const float*)d_in[23];
  const float* gwhh = (const float*)d_in[24];
  const float* Cw   = (const float*)d_in[25];

  const size_t hstE = (size_t)2 * 1024 * 128;
  int Tc = 128;
  while (Tc > 16){
    size_t needB = (hstE + (size_t)1024 * Tc * (3 * 128 + 2 * 128 + 2 * 32)) * 2 + 4096;
    if (needB <= ws_size) break;
    Tc >>= 1;
  }
  int NC = 1024 / Tc;
  size_t phiSz = (size_t)1024 * Tc * 128;   // elems; Hs slot same size
  size_t xmSz  = (size_t)1024 * Tc * 32;

  u16* hst  = (u16*)d_ws;
  u16* phiB = hst + hstE;
  u16* HsB  = phiB + 3 * phiSz;
  u16* xmB  = HsB + 2 * phiSz;

  hipMemsetAsync(d_out, 0, sizeof(float), stream);
  k_inith<<<1024, 256, 0, stream>>>(h0, hst);

  for (int j = 0; j <= NC + 2; j++){
    int flags = 0;
    if (j < NC) flags |= 1;                    // phiu(j)
    if (j >= 1 && j <= NC) flags |= 2;         // gru(j-1)
    if (j >= 2 && j <= NC + 1) flags |= 4;     // c1(j-2)
    if (j >= 3) flags |= 8;                    // c2(j-3)
    int s0 = j % 3, s1 = (j + 2) % 3, s2 = (j + 1) % 3;
    int hw = (j + 1) & 1, hc = j & 1;
    int xw = j & 1, xc = (j + 1) & 1;
    k_fused<<<448, 512, 0, stream>>>(
        u, y,
        puw0, pub0, puw1, pub1,
        dw0, db0, dw1, db1, xmw, xmb, xlw, xlb,
        pxw0, pxb0, pxw1, pxb1, mw0, mb0, mw1, mb1,
        Cw, gwih, gwhh,
        phiB + (size_t)s0 * phiSz, phiB + (size_t)s1 * phiSz, phiB + (size_t)s2 * phiSz,
        hst, HsB + (size_t)hw * phiSz, HsB + (size_t)hc * phiSz,
        xmB + (size_t)xw * xmSz, xmB + (size_t)xc * xmSz,
        (float*)d_out, j * Tc, (j - 3) * Tc, Tc, flags);
  }
}